// Round 1
// baseline (953.065 us; speedup 1.0000x reference)
//
#include <hip/hip_runtime.h>

#define NUSERS 250000
#define NITEMS 250000
#define NNODES 500000
#define NEDGES 1200000

// ---------------- degree / normalization ----------------

__global__ void k_init_deg(int* __restrict__ deg) {
    int n = blockIdx.x * blockDim.x + threadIdx.x;
    if (n < NNODES) deg[n] = 1;   // self-loop
}

__global__ void k_count_deg(const int* __restrict__ dst, int* __restrict__ deg) {
    int e = blockIdx.x * blockDim.x + threadIdx.x;
    if (e < NEDGES) atomicAdd(&deg[dst[e]], 1);
}

__global__ void k_dinv(const int* __restrict__ deg, float* __restrict__ dinv) {
    int n = blockIdx.x * blockDim.x + threadIdx.x;
    if (n < NNODES) dinv[n] = 1.0f / sqrtf((float)deg[n]);
}

// ---------------- layer 1: gather + x@W1, g = h*dinv, acc = g (self loop) ----------------
// wave-per-node; lane j computes h[j]; W1 column j lives in 64 VGPRs;
// x[k] broadcast via v_readlane (no LDS traffic).

__global__ __launch_bounds__(256) void k_layer1(
    const float* __restrict__ user_table, const float* __restrict__ item_table,
    const int*   __restrict__ user_ids,   const int*   __restrict__ item_ids,
    const float* __restrict__ W1, const float* __restrict__ dinv,
    float* __restrict__ g, float* __restrict__ acc)
{
    const int lane = threadIdx.x & 63;
    const int wid  = blockIdx.x * (blockDim.x >> 6) + (threadIdx.x >> 6);
    const int nw   = gridDim.x * (blockDim.x >> 6);

    float wcol[64];
#pragma unroll
    for (int k = 0; k < 64; ++k) wcol[k] = W1[k * 64 + lane];

    for (int n = wid; n < NNODES; n += nw) {
        const float* xr;
        if (n < NUSERS) xr = user_table + (size_t)user_ids[n] * 64;
        else            xr = item_table + (size_t)item_ids[n - NUSERS] * 64;
        float xv = xr[lane];
        float h = 0.0f;
#pragma unroll
        for (int k = 0; k < 64; ++k) {
            float xk = __int_as_float(__builtin_amdgcn_readlane(__float_as_int(xv), k));
            h = fmaf(xk, wcol[k], h);
        }
        float gv = h * dinv[n];
        g  [(size_t)n * 64 + lane] = gv;
        acc[(size_t)n * 64 + lane] = gv;   // self-loop contribution
    }
}

// ---------------- edge scatter: acc[d] += g[s], wave per edge ----------------

__global__ __launch_bounds__(256) void k_scatter(
    const int* __restrict__ src, const int* __restrict__ dst,
    const float* __restrict__ g, float* __restrict__ acc)
{
    int e    = blockIdx.x * (blockDim.x >> 6) + (threadIdx.x >> 6);
    int lane = threadIdx.x & 63;
    if (e < NEDGES) {
        int s = src[e], d = dst[e];
        float v = g[(size_t)s * 64 + lane];
        unsafeAtomicAdd(&acc[(size_t)d * 64 + lane], v);
    }
}

// ---------------- layer 2: x1 = relu(dinv*acc + b1); h2 = x1@W2; g2 = h2*dinv ----------------
// in-place safe: accout[n] depends only on accin[n] (read before write, same wave)

__global__ __launch_bounds__(256) void k_layer2(
    const float* __restrict__ W2, const float* __restrict__ b1,
    const float* __restrict__ dinv,
    const float* __restrict__ accin, float* __restrict__ g, float* __restrict__ accout)
{
    const int lane = threadIdx.x & 63;
    const int wid  = blockIdx.x * (blockDim.x >> 6) + (threadIdx.x >> 6);
    const int nw   = gridDim.x * (blockDim.x >> 6);

    float wcol[64];
#pragma unroll
    for (int k = 0; k < 64; ++k) wcol[k] = W2[k * 64 + lane];
    float bb = b1[lane];

    for (int n = wid; n < NNODES; n += nw) {
        float dn = dinv[n];
        float a  = accin[(size_t)n * 64 + lane];
        float x1 = fmaxf(fmaf(dn, a, bb), 0.0f);
        float h = 0.0f;
#pragma unroll
        for (int k = 0; k < 64; ++k) {
            float xk = __int_as_float(__builtin_amdgcn_readlane(__float_as_int(x1), k));
            h = fmaf(xk, wcol[k], h);
        }
        float gv = h * dn;
        g     [(size_t)n * 64 + lane] = gv;
        accout[(size_t)n * 64 + lane] = gv;   // self-loop
    }
}

// ---------------- final: out[b] = [relu-row(u), relu-row(i)] . Wp + bp ----------------

__global__ __launch_bounds__(256) void k_final(
    const int* __restrict__ user_ids, const int* __restrict__ item_ids,
    const float* __restrict__ dinv, const float* __restrict__ acc,
    const float* __restrict__ b2, const float* __restrict__ Wp,
    const float* __restrict__ bp, float* __restrict__ out)
{
    int b    = blockIdx.x * (blockDim.x >> 6) + (threadIdx.x >> 6);
    int lane = threadIdx.x & 63;
    if (b >= NUSERS) return;
    int nu = user_ids[b];
    int ni = NUSERS + item_ids[b];
    float bb = b2[lane];
    float xu = fmaxf(fmaf(dinv[nu], acc[(size_t)nu * 64 + lane], bb), 0.0f);
    float xi = fmaxf(fmaf(dinv[ni], acc[(size_t)ni * 64 + lane], bb), 0.0f);
    float t  = xu * Wp[lane] + xi * Wp[64 + lane];
#pragma unroll
    for (int off = 32; off > 0; off >>= 1) t += __shfl_xor(t, off, 64);
    if (lane == 0) out[b] = t + bp[0];
}

// ---------------- launch ----------------

extern "C" void kernel_launch(void* const* d_in, const int* in_sizes, int n_in,
                              void* d_out, int out_size, void* d_ws, size_t ws_size,
                              hipStream_t stream)
{
    const float* user_table = (const float*)d_in[0];
    const float* item_table = (const float*)d_in[1];
    const float* W1 = (const float*)d_in[2];
    const float* b1 = (const float*)d_in[3];
    const float* W2 = (const float*)d_in[4];
    const float* b2 = (const float*)d_in[5];
    const float* Wp = (const float*)d_in[6];
    const float* bp = (const float*)d_in[7];
    const int* edge = (const int*)d_in[8];      // [2, NEDGES] row-major
    const int* uid  = (const int*)d_in[9];
    const int* iid  = (const int*)d_in[10];
    float* out = (float*)d_out;

    const int* src = edge;
    const int* dst = edge + NEDGES;

    char* ws = (char*)d_ws;
    int*   deg  = (int*)  (ws + 0);
    float* dinv = (float*)(ws + (4u << 20));
    float* g    = (float*)(ws + (8u << 20));
    float* acc  = (float*)(ws + (8u << 20) + (size_t)NNODES * 64 * 4);

    k_init_deg <<<(NNODES + 255) / 256, 256, 0, stream>>>(deg);
    k_count_deg<<<(NEDGES + 255) / 256, 256, 0, stream>>>(dst, deg);
    k_dinv     <<<(NNODES + 255) / 256, 256, 0, stream>>>(deg, dinv);

    k_layer1<<<2048, 256, 0, stream>>>(user_table, item_table, uid, iid, W1, dinv, g, acc);
    k_scatter<<<(NEDGES + 3) / 4, 256, 0, stream>>>(src, dst, g, acc);

    k_layer2<<<2048, 256, 0, stream>>>(W2, b1, dinv, acc, g, acc);
    k_scatter<<<(NEDGES + 3) / 4, 256, 0, stream>>>(src, dst, g, acc);

    k_final<<<(NUSERS + 3) / 4, 256, 0, stream>>>(uid, iid, dinv, acc, b2, Wp, bp, out);
}

// Round 3
// 698.928 us; speedup vs baseline: 1.3636x; 1.3636x over previous
//
#include <hip/hip_runtime.h>

#define NUSERS 250000
#define NITEMS 250000
#define NNODES 500000
#define NEDGES 1200000
#define NBLK   1954          // ceil(NNODES/256)

// ---------------- degree / normalization ----------------

__global__ void k_zero_deg(int* __restrict__ deg) {
    int n = blockIdx.x * blockDim.x + threadIdx.x;
    if (n < NNODES) deg[n] = 0;   // real in-edges only; self-loop added in dinv
}

__global__ void k_count_deg(const int* __restrict__ dst, int* __restrict__ deg) {
    int e = blockIdx.x * blockDim.x + threadIdx.x;
    if (e < NEDGES) atomicAdd(&deg[dst[e]], 1);
}

__global__ void k_dinv(const int* __restrict__ deg, float* __restrict__ dinv) {
    int n = blockIdx.x * blockDim.x + threadIdx.x;
    if (n < NNODES) dinv[n] = 1.0f / sqrtf((float)(deg[n] + 1));
}

// ---------------- CSR build: scan of deg -> offsets, then placement ----------------

__global__ __launch_bounds__(256) void k_block_sums(const int* __restrict__ deg,
                                                    int* __restrict__ partials) {
    __shared__ int sm[256];
    int t = threadIdx.x;
    int n = blockIdx.x * 256 + t;
    int v = (n < NNODES) ? deg[n] : 0;
    sm[t] = v; __syncthreads();
    for (int d = 128; d > 0; d >>= 1) {
        if (t < d) sm[t] += sm[t + d];
        __syncthreads();
    }
    if (t == 0) partials[blockIdx.x] = sm[0];
}

__global__ __launch_bounds__(256) void k_scan_partials(int* __restrict__ partials) {
    __shared__ int sm[256];
    int t = threadIdx.x;
    int v[8]; int s = 0;
#pragma unroll
    for (int i = 0; i < 8; ++i) {
        int idx = t * 8 + i;
        v[i] = (idx < NBLK) ? partials[idx] : 0;
        s += v[i];
    }
    sm[t] = s; __syncthreads();
    for (int d = 1; d < 256; d <<= 1) {
        int x = (t >= d) ? sm[t - d] : 0;
        __syncthreads();
        sm[t] += x;
        __syncthreads();
    }
    int run = sm[t] - s;            // exclusive prefix of this thread's chunk
#pragma unroll
    for (int i = 0; i < 8; ++i) {
        int idx = t * 8 + i;
        if (idx < NBLK) partials[idx] = run;
        run += v[i];
    }
}

// offsets[n] = global exclusive scan; cursor aliases deg (overwritten here)
__global__ __launch_bounds__(256) void k_scan_blocks(const int* __restrict__ partials,
                                                     int* __restrict__ degcursor,
                                                     int* __restrict__ offsets) {
    __shared__ int sm[256];
    int t = threadIdx.x;
    int n = blockIdx.x * 256 + t;
    int v = (n < NNODES) ? degcursor[n] : 0;
    sm[t] = v; __syncthreads();
    for (int d = 1; d < 256; d <<= 1) {
        int x = (t >= d) ? sm[t - d] : 0;
        __syncthreads();
        sm[t] += x;
        __syncthreads();
    }
    int off = partials[blockIdx.x] + sm[t] - v;   // exclusive
    if (n < NNODES) {
        offsets[n]   = off;
        degcursor[n] = off;        // becomes atomic cursor for placement
        if (n == NNODES - 1) offsets[NNODES] = off + v;
    }
}

__global__ void k_place(const int* __restrict__ src, const int* __restrict__ dst,
                        int* __restrict__ cursor, int* __restrict__ csr_src) {
    int e = blockIdx.x * blockDim.x + threadIdx.x;
    if (e < NEDGES) {
        int pos = atomicAdd(&cursor[dst[e]], 1);
        csr_src[pos] = src[e];
    }
}

// ---------------- layer 1: gather emb + x@W1, g1 = h*dinv ----------------

__global__ __launch_bounds__(256) void k_layer1(
    const float* __restrict__ user_table, const float* __restrict__ item_table,
    const int*   __restrict__ user_ids,   const int*   __restrict__ item_ids,
    const float* __restrict__ W1, const float* __restrict__ dinv,
    float* __restrict__ g1)
{
    const int lane = threadIdx.x & 63;
    const int wid  = blockIdx.x * (blockDim.x >> 6) + (threadIdx.x >> 6);
    const int nw   = gridDim.x * (blockDim.x >> 6);

    float wcol[64];
#pragma unroll
    for (int k = 0; k < 64; ++k) wcol[k] = W1[k * 64 + lane];

    for (int n = wid; n < NNODES; n += nw) {
        const float* xr;
        if (n < NUSERS) xr = user_table + (size_t)user_ids[n] * 64;
        else            xr = item_table + (size_t)item_ids[n - NUSERS] * 64;
        float xv = xr[lane];
        float h = 0.0f;
#pragma unroll
        for (int k = 0; k < 64; ++k) {
            float xk = __int_as_float(__builtin_amdgcn_readlane(__float_as_int(xv), k));
            h = fmaf(xk, wcol[k], h);
        }
        g1[(size_t)n * 64 + lane] = h * dinv[n];
    }
}

// ---------------- gather(1) + layer2 fused:
//   sum = g1[n] + sum_{incoming e} g1[src[e]]
//   x1 = relu(dinv*sum + b1);  g2 = (x1@W2)*dinv ----------------

__global__ __launch_bounds__(256) void k_gather2(
    const int* __restrict__ off, const int* __restrict__ csr,
    const float* __restrict__ W2, const float* __restrict__ b1,
    const float* __restrict__ dinv,
    const float* __restrict__ g1, float* __restrict__ g2)
{
    const int lane = threadIdx.x & 63;
    const int wid  = blockIdx.x * (blockDim.x >> 6) + (threadIdx.x >> 6);
    const int nw   = gridDim.x * (blockDim.x >> 6);

    float wcol[64];
#pragma unroll
    for (int k = 0; k < 64; ++k) wcol[k] = W2[k * 64 + lane];
    float bb = b1[lane];

    for (int n = wid; n < NNODES; n += nw) {
        float sum = g1[(size_t)n * 64 + lane];   // self-loop
        int o = off[n], oe = off[n + 1];
        for (; o + 4 <= oe; o += 4) {
            int s0 = csr[o], s1 = csr[o+1], s2 = csr[o+2], s3 = csr[o+3];
            float a = g1[(size_t)s0 * 64 + lane];
            float b = g1[(size_t)s1 * 64 + lane];
            float c = g1[(size_t)s2 * 64 + lane];
            float d = g1[(size_t)s3 * 64 + lane];
            sum += (a + b) + (c + d);
        }
        for (; o < oe; ++o) sum += g1[(size_t)csr[o] * 64 + lane];

        float dn = dinv[n];
        float x1 = fmaxf(fmaf(dn, sum, bb), 0.0f);
        float h = 0.0f;
#pragma unroll
        for (int k = 0; k < 64; ++k) {
            float xk = __int_as_float(__builtin_amdgcn_readlane(__float_as_int(x1), k));
            h = fmaf(xk, wcol[k], h);
        }
        g2[(size_t)n * 64 + lane] = h * dn;
    }
}

// ---------------- gather(2) + relu + Wp-dot fused -> per-node scalar ----------------

__global__ __launch_bounds__(256) void k_gather_final(
    const int* __restrict__ off, const int* __restrict__ csr,
    const float* __restrict__ b2, const float* __restrict__ Wp,
    const float* __restrict__ dinv,
    const float* __restrict__ g2, float* __restrict__ pscore)
{
    const int lane = threadIdx.x & 63;
    const int wid  = blockIdx.x * (blockDim.x >> 6) + (threadIdx.x >> 6);
    const int nw   = gridDim.x * (blockDim.x >> 6);

    float bb  = b2[lane];
    float wpu = Wp[lane];
    float wpi = Wp[64 + lane];

    for (int n = wid; n < NNODES; n += nw) {
        float sum = g2[(size_t)n * 64 + lane];   // self-loop
        int o = off[n], oe = off[n + 1];
        for (; o + 4 <= oe; o += 4) {
            int s0 = csr[o], s1 = csr[o+1], s2 = csr[o+2], s3 = csr[o+3];
            float a = g2[(size_t)s0 * 64 + lane];
            float b = g2[(size_t)s1 * 64 + lane];
            float c = g2[(size_t)s2 * 64 + lane];
            float d = g2[(size_t)s3 * 64 + lane];
            sum += (a + b) + (c + d);
        }
        for (; o < oe; ++o) sum += g2[(size_t)csr[o] * 64 + lane];

        float x2 = fmaxf(fmaf(dinv[n], sum, bb), 0.0f);
        float t  = x2 * ((n < NUSERS) ? wpu : wpi);
#pragma unroll
        for (int o2 = 32; o2 > 0; o2 >>= 1) t += __shfl_xor(t, o2, 64);
        if (lane == 0) pscore[n] = t;
    }
}

__global__ void k_pairs(const int* __restrict__ user_ids, const int* __restrict__ item_ids,
                        const float* __restrict__ pscore, const float* __restrict__ bp,
                        float* __restrict__ out)
{
    int b = blockIdx.x * blockDim.x + threadIdx.x;
    if (b < NUSERS)
        out[b] = pscore[user_ids[b]] + pscore[NUSERS + item_ids[b]] + bp[0];
}

// ---------------- launch ----------------
// Workspace layout (byte-exact, total 266,808,064 B < 256 MiB):
//   deg/cursor :         0 ..   2,000,000   (reused as pscore after k_place)
//   dinv       : 2,000,000 ..   4,000,000
//   offsets    : 4,000,000 ..   6,000,004   (NNODES+1 ints)
//   partials   : 6,000,128 ..   6,007,944   (NBLK ints)
//   csr_src    : 6,008,000 ..  10,808,000   (NEDGES ints)
//   g1         : 10,808,064 .. 138,808,064  (NNODES*64 f32)
//   g2         : 138,808,064 .. 266,808,064

extern "C" void kernel_launch(void* const* d_in, const int* in_sizes, int n_in,
                              void* d_out, int out_size, void* d_ws, size_t ws_size,
                              hipStream_t stream)
{
    const float* user_table = (const float*)d_in[0];
    const float* item_table = (const float*)d_in[1];
    const float* W1 = (const float*)d_in[2];
    const float* b1 = (const float*)d_in[3];
    const float* W2 = (const float*)d_in[4];
    const float* b2 = (const float*)d_in[5];
    const float* Wp = (const float*)d_in[6];
    const float* bp = (const float*)d_in[7];
    const int* edge = (const int*)d_in[8];      // [2, NEDGES] row-major
    const int* uid  = (const int*)d_in[9];
    const int* iid  = (const int*)d_in[10];
    float* out = (float*)d_out;

    const int* src = edge;
    const int* dst = edge + NEDGES;

    char* ws = (char*)d_ws;
    int*   deg      = (int*)  (ws + 0);
    float* dinv     = (float*)(ws + 2000000);
    int*   offsets  = (int*)  (ws + 4000000);
    int*   partials = (int*)  (ws + 6000128);
    int*   csr_src  = (int*)  (ws + 6008000);
    float* g1       = (float*)(ws + 10808064);
    float* g2       = (float*)(ws + 138808064);
    float* pscore   = (float*)(ws + 0);          // aliases deg (dead after k_place)

    k_zero_deg     <<<NBLK, 256, 0, stream>>>(deg);
    k_count_deg    <<<(NEDGES + 255) / 256, 256, 0, stream>>>(dst, deg);
    k_dinv         <<<NBLK, 256, 0, stream>>>(deg, dinv);
    k_block_sums   <<<NBLK, 256, 0, stream>>>(deg, partials);
    k_scan_partials<<<1, 256, 0, stream>>>(partials);
    k_scan_blocks  <<<NBLK, 256, 0, stream>>>(partials, deg, offsets);
    k_place        <<<(NEDGES + 255) / 256, 256, 0, stream>>>(src, dst, deg, csr_src);

    k_layer1       <<<2048, 256, 0, stream>>>(user_table, item_table, uid, iid, W1, dinv, g1);
    k_gather2      <<<2048, 256, 0, stream>>>(offsets, csr_src, W2, b1, dinv, g1, g2);
    k_gather_final <<<2048, 256, 0, stream>>>(offsets, csr_src, b2, Wp, dinv, g2, pscore);
    k_pairs        <<<(NUSERS + 255) / 256, 256, 0, stream>>>(uid, iid, pscore, bp, out);
}

// Round 4
// 653.249 us; speedup vs baseline: 1.4590x; 1.0699x over previous
//
#include <hip/hip_runtime.h>

#define NUSERS 250000
#define NITEMS 250000
#define NNODES 500000
#define NEDGES 1200000
#define NBLK   1954          // ceil(NNODES/256)

typedef _Float16 half_t;

// ---------------- degree / normalization ----------------

__global__ void k_zero_deg(int* __restrict__ deg) {
    int n = blockIdx.x * blockDim.x + threadIdx.x;
    if (n < NNODES) deg[n] = 0;   // real in-edges only; self-loop added in dinv
}

__global__ void k_count_deg(const int* __restrict__ dst, int* __restrict__ deg) {
    int e = blockIdx.x * blockDim.x + threadIdx.x;
    if (e < NEDGES) atomicAdd(&deg[dst[e]], 1);
}

__global__ void k_dinv(const int* __restrict__ deg, float* __restrict__ dinv) {
    int n = blockIdx.x * blockDim.x + threadIdx.x;
    if (n < NNODES) dinv[n] = 1.0f / sqrtf((float)(deg[n] + 1));
}

// ---------------- CSR build: scan of deg -> offsets, then placement ----------------

__global__ __launch_bounds__(256) void k_block_sums(const int* __restrict__ deg,
                                                    int* __restrict__ partials) {
    __shared__ int sm[256];
    int t = threadIdx.x;
    int n = blockIdx.x * 256 + t;
    int v = (n < NNODES) ? deg[n] : 0;
    sm[t] = v; __syncthreads();
    for (int d = 128; d > 0; d >>= 1) {
        if (t < d) sm[t] += sm[t + d];
        __syncthreads();
    }
    if (t == 0) partials[blockIdx.x] = sm[0];
}

__global__ __launch_bounds__(256) void k_scan_partials(int* __restrict__ partials) {
    __shared__ int sm[256];
    int t = threadIdx.x;
    int v[8]; int s = 0;
#pragma unroll
    for (int i = 0; i < 8; ++i) {
        int idx = t * 8 + i;
        v[i] = (idx < NBLK) ? partials[idx] : 0;
        s += v[i];
    }
    sm[t] = s; __syncthreads();
    for (int d = 1; d < 256; d <<= 1) {
        int x = (t >= d) ? sm[t - d] : 0;
        __syncthreads();
        sm[t] += x;
        __syncthreads();
    }
    int run = sm[t] - s;            // exclusive prefix of this thread's chunk
#pragma unroll
    for (int i = 0; i < 8; ++i) {
        int idx = t * 8 + i;
        if (idx < NBLK) partials[idx] = run;
        run += v[i];
    }
}

__global__ __launch_bounds__(256) void k_scan_blocks(const int* __restrict__ partials,
                                                     int* __restrict__ degcursor,
                                                     int* __restrict__ offsets) {
    __shared__ int sm[256];
    int t = threadIdx.x;
    int n = blockIdx.x * 256 + t;
    int v = (n < NNODES) ? degcursor[n] : 0;
    sm[t] = v; __syncthreads();
    for (int d = 1; d < 256; d <<= 1) {
        int x = (t >= d) ? sm[t - d] : 0;
        __syncthreads();
        sm[t] += x;
        __syncthreads();
    }
    int off = partials[blockIdx.x] + sm[t] - v;   // exclusive
    if (n < NNODES) {
        offsets[n]   = off;
        degcursor[n] = off;        // becomes atomic cursor for placement
        if (n == NNODES - 1) offsets[NNODES] = off + v;
    }
}

__global__ void k_place(const int* __restrict__ src, const int* __restrict__ dst,
                        int* __restrict__ cursor, int* __restrict__ csr_src) {
    int e = blockIdx.x * blockDim.x + threadIdx.x;
    if (e < NEDGES) {
        int pos = atomicAdd(&cursor[dst[e]], 1);
        csr_src[pos] = src[e];
    }
}

// ---------------- layer 1: gather emb + x@W1, g1 = (h*dinv) as fp16 ----------------
// 4 consecutive nodes per wave: 4 independent random table-row loads in flight.

__global__ __launch_bounds__(256) void k_layer1(
    const float* __restrict__ user_table, const float* __restrict__ item_table,
    const int*   __restrict__ user_ids,   const int*   __restrict__ item_ids,
    const float* __restrict__ W1, const float* __restrict__ dinv,
    half_t* __restrict__ g1)
{
    const int lane = threadIdx.x & 63;
    const int wid  = blockIdx.x * (blockDim.x >> 6) + (threadIdx.x >> 6);
    const int nw   = gridDim.x * (blockDim.x >> 6);

    float wcol[64];
#pragma unroll
    for (int k = 0; k < 64; ++k) wcol[k] = W1[k * 64 + lane];

    for (int b = wid; b * 4 < NNODES; b += nw) {
        const int n0 = b * 4;                      // NUSERS%4==0: block never straddles
        float xv[4];
#pragma unroll
        for (int j = 0; j < 4; ++j) {
            int n = n0 + j;
            const float* xr = (n < NUSERS)
                ? user_table + (size_t)user_ids[n] * 64
                : item_table + (size_t)item_ids[n - NUSERS] * 64;
            xv[j] = xr[lane];
        }
#pragma unroll
        for (int j = 0; j < 4; ++j) {
            float h = 0.0f;
#pragma unroll
            for (int k = 0; k < 64; ++k) {
                float xk = __int_as_float(__builtin_amdgcn_readlane(__float_as_int(xv[j]), k));
                h = fmaf(xk, wcol[k], h);
            }
            g1[(size_t)(n0 + j) * 64 + lane] = (half_t)(h * dinv[n0 + j]);
        }
    }
}

// ---------------- gather(1) + layer2 fused (4 nodes/wave, interleaved chains) ----------------

__global__ __launch_bounds__(256) void k_gather2(
    const int* __restrict__ off, const int* __restrict__ csr,
    const float* __restrict__ W2, const float* __restrict__ b1,
    const float* __restrict__ dinv,
    const half_t* __restrict__ g1, half_t* __restrict__ g2)
{
    const int lane = threadIdx.x & 63;
    const int wid  = blockIdx.x * (blockDim.x >> 6) + (threadIdx.x >> 6);
    const int nw   = gridDim.x * (blockDim.x >> 6);

    float wcol[64];
#pragma unroll
    for (int k = 0; k < 64; ++k) wcol[k] = W2[k * 64 + lane];
    float bb = b1[lane];

    for (int b = wid; b * 4 < NNODES; b += nw) {
        const int n0 = b * 4;
        int o[4], oe[4];
        int e0 = off[n0], e1 = off[n0+1], e2 = off[n0+2], e3 = off[n0+3], e4 = off[n0+4];
        o[0]=e0; oe[0]=e1;  o[1]=e1; oe[1]=e2;  o[2]=e2; oe[2]=e3;  o[3]=e3; oe[3]=e4;

        float sum[4];
#pragma unroll
        for (int j = 0; j < 4; ++j)
            sum[j] = (float)g1[(size_t)(n0 + j) * 64 + lane];   // self-loop

        while ((o[0] < oe[0]) | (o[1] < oe[1]) | (o[2] < oe[2]) | (o[3] < oe[3])) {
            bool va[4]; int s[4];
#pragma unroll
            for (int j = 0; j < 4; ++j) {
                va[j] = o[j] < oe[j];
                s[j] = csr[va[j] ? o[j] : 0];        // always load (safe addr) -> 4 in flight
            }
            float r[4];
#pragma unroll
            for (int j = 0; j < 4; ++j)
                r[j] = (float)g1[(size_t)(va[j] ? s[j] : 0) * 64 + lane];  // 4 in flight
#pragma unroll
            for (int j = 0; j < 4; ++j)
                if (va[j]) { sum[j] += r[j]; ++o[j]; }
        }

#pragma unroll
        for (int j = 0; j < 4; ++j) {
            float dn = dinv[n0 + j];
            float x1 = fmaxf(fmaf(dn, sum[j], bb), 0.0f);
            float h = 0.0f;
#pragma unroll
            for (int k = 0; k < 64; ++k) {
                float xk = __int_as_float(__builtin_amdgcn_readlane(__float_as_int(x1), k));
                h = fmaf(xk, wcol[k], h);
            }
            g2[(size_t)(n0 + j) * 64 + lane] = (half_t)(h * dn);
        }
    }
}

// ---------------- gather(2) + relu + Wp-dot fused -> per-node scalar ----------------

__global__ __launch_bounds__(256) void k_gather_final(
    const int* __restrict__ off, const int* __restrict__ csr,
    const float* __restrict__ b2, const float* __restrict__ Wp,
    const float* __restrict__ dinv,
    const half_t* __restrict__ g2, float* __restrict__ pscore)
{
    const int lane = threadIdx.x & 63;
    const int wid  = blockIdx.x * (blockDim.x >> 6) + (threadIdx.x >> 6);
    const int nw   = gridDim.x * (blockDim.x >> 6);

    float bb  = b2[lane];
    float wpu = Wp[lane];
    float wpi = Wp[64 + lane];

    for (int b = wid; b * 4 < NNODES; b += nw) {
        const int n0 = b * 4;
        int o[4], oe[4];
        int e0 = off[n0], e1 = off[n0+1], e2 = off[n0+2], e3 = off[n0+3], e4 = off[n0+4];
        o[0]=e0; oe[0]=e1;  o[1]=e1; oe[1]=e2;  o[2]=e2; oe[2]=e3;  o[3]=e3; oe[3]=e4;

        float sum[4];
#pragma unroll
        for (int j = 0; j < 4; ++j)
            sum[j] = (float)g2[(size_t)(n0 + j) * 64 + lane];   // self-loop

        while ((o[0] < oe[0]) | (o[1] < oe[1]) | (o[2] < oe[2]) | (o[3] < oe[3])) {
            bool va[4]; int s[4];
#pragma unroll
            for (int j = 0; j < 4; ++j) {
                va[j] = o[j] < oe[j];
                s[j] = csr[va[j] ? o[j] : 0];
            }
            float r[4];
#pragma unroll
            for (int j = 0; j < 4; ++j)
                r[j] = (float)g2[(size_t)(va[j] ? s[j] : 0) * 64 + lane];
#pragma unroll
            for (int j = 0; j < 4; ++j)
                if (va[j]) { sum[j] += r[j]; ++o[j]; }
        }

        float wsel = (n0 < NUSERS) ? wpu : wpi;    // whole 4-block on one side
#pragma unroll
        for (int j = 0; j < 4; ++j) {
            float x2 = fmaxf(fmaf(dinv[n0 + j], sum[j], bb), 0.0f);
            float t  = x2 * wsel;
#pragma unroll
            for (int o2 = 32; o2 > 0; o2 >>= 1) t += __shfl_xor(t, o2, 64);
            if (lane == 0) pscore[n0 + j] = t;
        }
    }
}

__global__ void k_pairs(const int* __restrict__ user_ids, const int* __restrict__ item_ids,
                        const float* __restrict__ pscore, const float* __restrict__ bp,
                        float* __restrict__ out)
{
    int b = blockIdx.x * blockDim.x + threadIdx.x;
    if (b < NUSERS)
        out[b] = pscore[user_ids[b]] + pscore[NUSERS + item_ids[b]] + bp[0];
}

// ---------------- launch ----------------
// Workspace layout (byte-exact):
//   deg/cursor :          0 ..   2,000,000   (reused as pscore after k_place)
//   dinv       :  2,000,000 ..   4,000,000
//   offsets    :  4,000,000 ..   6,000,004   (NNODES+1 ints)
//   partials   :  6,000,128 ..   6,007,944   (NBLK ints)
//   csr_src    :  6,008,000 ..  10,808,000   (NEDGES ints)
//   g1 (fp16)  : 10,808,064 ..  74,808,064   (NNODES*64 half)
//   g2 (fp16)  : 74,808,064 .. 138,808,064

extern "C" void kernel_launch(void* const* d_in, const int* in_sizes, int n_in,
                              void* d_out, int out_size, void* d_ws, size_t ws_size,
                              hipStream_t stream)
{
    const float* user_table = (const float*)d_in[0];
    const float* item_table = (const float*)d_in[1];
    const float* W1 = (const float*)d_in[2];
    const float* b1 = (const float*)d_in[3];
    const float* W2 = (const float*)d_in[4];
    const float* b2 = (const float*)d_in[5];
    const float* Wp = (const float*)d_in[6];
    const float* bp = (const float*)d_in[7];
    const int* edge = (const int*)d_in[8];      // [2, NEDGES] row-major
    const int* uid  = (const int*)d_in[9];
    const int* iid  = (const int*)d_in[10];
    float* out = (float*)d_out;

    const int* src = edge;
    const int* dst = edge + NEDGES;

    char* ws = (char*)d_ws;
    int*    deg      = (int*)   (ws + 0);
    float*  dinv     = (float*) (ws + 2000000);
    int*    offsets  = (int*)   (ws + 4000000);
    int*    partials = (int*)   (ws + 6000128);
    int*    csr_src  = (int*)   (ws + 6008000);
    half_t* g1       = (half_t*)(ws + 10808064);
    half_t* g2       = (half_t*)(ws + 74808064);
    float*  pscore   = (float*) (ws + 0);        // aliases deg (dead after k_place)

    k_zero_deg     <<<NBLK, 256, 0, stream>>>(deg);
    k_count_deg    <<<(NEDGES + 255) / 256, 256, 0, stream>>>(dst, deg);
    k_dinv         <<<NBLK, 256, 0, stream>>>(deg, dinv);
    k_block_sums   <<<NBLK, 256, 0, stream>>>(deg, partials);
    k_scan_partials<<<1, 256, 0, stream>>>(partials);
    k_scan_blocks  <<<NBLK, 256, 0, stream>>>(partials, deg, offsets);
    k_place        <<<(NEDGES + 255) / 256, 256, 0, stream>>>(src, dst, deg, csr_src);

    k_layer1       <<<2048, 256, 0, stream>>>(user_table, item_table, uid, iid, W1, dinv, g1);
    k_gather2      <<<2048, 256, 0, stream>>>(offsets, csr_src, W2, b1, dinv, g1, g2);
    k_gather_final <<<2048, 256, 0, stream>>>(offsets, csr_src, b2, Wp, dinv, g2, pscore);
    k_pairs        <<<(NUSERS + 255) / 256, 256, 0, stream>>>(uid, iid, pscore, bp, out);
}

// Round 5
// 451.235 us; speedup vs baseline: 2.1121x; 1.4477x over previous
//
#include <hip/hip_runtime.h>

#define NUSERS 250000
#define NITEMS 250000
#define NNODES 500000
#define NEDGES 1200000
#define NBLK   1954          // ceil(NNODES/256)

typedef _Float16 half_t;
typedef _Float16 half8 __attribute__((ext_vector_type(8)));
typedef _Float16 half4 __attribute__((ext_vector_type(4)));
typedef float    f32x4 __attribute__((ext_vector_type(4)));

// ---------------- degree / normalization ----------------

__global__ void k_zero_deg(int* __restrict__ deg) {
    int n = blockIdx.x * blockDim.x + threadIdx.x;
    if (n < NNODES) deg[n] = 0;
}

__global__ void k_count_deg(const int* __restrict__ dst, int* __restrict__ deg) {
    int e = blockIdx.x * blockDim.x + threadIdx.x;
    if (e < NEDGES) atomicAdd(&deg[dst[e]], 1);
}

__global__ void k_dinv(const int* __restrict__ deg, float* __restrict__ dinv) {
    int n = blockIdx.x * blockDim.x + threadIdx.x;
    if (n < NNODES) dinv[n] = 1.0f / sqrtf((float)(deg[n] + 1));
}

// ---------------- CSR build ----------------

__global__ __launch_bounds__(256) void k_block_sums(const int* __restrict__ deg,
                                                    int* __restrict__ partials) {
    __shared__ int sm[256];
    int t = threadIdx.x;
    int n = blockIdx.x * 256 + t;
    int v = (n < NNODES) ? deg[n] : 0;
    sm[t] = v; __syncthreads();
    for (int d = 128; d > 0; d >>= 1) {
        if (t < d) sm[t] += sm[t + d];
        __syncthreads();
    }
    if (t == 0) partials[blockIdx.x] = sm[0];
}

__global__ __launch_bounds__(256) void k_scan_partials(int* __restrict__ partials) {
    __shared__ int sm[256];
    int t = threadIdx.x;
    int v[8]; int s = 0;
#pragma unroll
    for (int i = 0; i < 8; ++i) {
        int idx = t * 8 + i;
        v[i] = (idx < NBLK) ? partials[idx] : 0;
        s += v[i];
    }
    sm[t] = s; __syncthreads();
    for (int d = 1; d < 256; d <<= 1) {
        int x = (t >= d) ? sm[t - d] : 0;
        __syncthreads();
        sm[t] += x;
        __syncthreads();
    }
    int run = sm[t] - s;
#pragma unroll
    for (int i = 0; i < 8; ++i) {
        int idx = t * 8 + i;
        if (idx < NBLK) partials[idx] = run;
        run += v[i];
    }
}

__global__ __launch_bounds__(256) void k_scan_blocks(const int* __restrict__ partials,
                                                     int* __restrict__ degcursor,
                                                     int* __restrict__ offsets) {
    __shared__ int sm[256];
    int t = threadIdx.x;
    int n = blockIdx.x * 256 + t;
    int v = (n < NNODES) ? degcursor[n] : 0;
    sm[t] = v; __syncthreads();
    for (int d = 1; d < 256; d <<= 1) {
        int x = (t >= d) ? sm[t - d] : 0;
        __syncthreads();
        sm[t] += x;
        __syncthreads();
    }
    int off = partials[blockIdx.x] + sm[t] - v;
    if (n < NNODES) {
        offsets[n]   = off;
        degcursor[n] = off;
        if (n == NNODES - 1) offsets[NNODES] = off + v;
    }
}

__global__ void k_place(const int* __restrict__ src, const int* __restrict__ dst,
                        int* __restrict__ cursor, int* __restrict__ csr_src) {
    int e = blockIdx.x * blockDim.x + threadIdx.x;
    if (e < NEDGES) {
        int pos = atomicAdd(&cursor[dst[e]], 1);
        csr_src[pos] = src[e];
    }
}

// ---------------- MFMA matmul kernels ----------------
// Tile: 16 nodes x 64 features, via mfma_f32_16x16x32_f16.
// A: lane holds row (lane&15), k = 32q + 8*(lane>>4) + j  (q = k-chunk)
// B: lane holds col-slot (lane&15), same k formula; out-feature = 4*(lane&15)+c
//   (same k-fill on A and B => any hw k-permutation cancels)
// C/D (verified): row=(lane>>4)*4+reg, col=lane&15 -> node=(lane>>4)*4+r, feat=4*(lane&15)+c

__device__ __forceinline__ void build_bfrags(const float* __restrict__ W,
                                             int lg, int cl, half8 bf[2][4]) {
#pragma unroll
    for (int q = 0; q < 2; ++q)
#pragma unroll
        for (int c = 0; c < 4; ++c) {
            half8 v;
#pragma unroll
            for (int j = 0; j < 8; ++j)
                v[j] = (half_t)W[(32 * q + 8 * lg + j) * 64 + 4 * cl + c];
            bf[q][c] = v;
        }
}

// g = (gather(emb) @ W1) * dinv   [fp16 out]
__global__ __launch_bounds__(256) void k_mm1(
    const float* __restrict__ user_table, const float* __restrict__ item_table,
    const int* __restrict__ uid, const int* __restrict__ iid,
    const float* __restrict__ W1, const float* __restrict__ dinv,
    half_t* __restrict__ g)
{
    const int lane = threadIdx.x & 63;
    const int lg = lane >> 4, cl = lane & 15;
    const int wid = blockIdx.x * (blockDim.x >> 6) + (threadIdx.x >> 6);
    const int nw  = gridDim.x * (blockDim.x >> 6);

    half8 bf[2][4];
    build_bfrags(W1, lg, cl, bf);
    const f32x4 zacc = {0.f, 0.f, 0.f, 0.f};

    for (int t = wid; t < NNODES / 16; t += nw) {
        const int n0 = t * 16;
        const int na = n0 + cl;                    // A-row node (tiles never straddle: NUSERS%16==0)
        const float* p = (na < NUSERS)
            ? user_table + (size_t)uid[na] * 64
            : item_table + (size_t)iid[na - NUSERS] * 64;
        f32x4 u0 = *(const f32x4*)(p + 8 * lg);
        f32x4 u1 = *(const f32x4*)(p + 8 * lg + 4);
        f32x4 u2 = *(const f32x4*)(p + 8 * lg + 32);
        f32x4 u3 = *(const f32x4*)(p + 8 * lg + 36);
        half8 a0, a1;
#pragma unroll
        for (int j = 0; j < 4; ++j) {
            a0[j] = (half_t)u0[j]; a0[4 + j] = (half_t)u1[j];
            a1[j] = (half_t)u2[j]; a1[4 + j] = (half_t)u3[j];
        }
        f32x4 acc[4];
#pragma unroll
        for (int c = 0; c < 4; ++c) {
            acc[c] = __builtin_amdgcn_mfma_f32_16x16x32_f16(a0, bf[0][c], zacc, 0, 0, 0);
            acc[c] = __builtin_amdgcn_mfma_f32_16x16x32_f16(a1, bf[1][c], acc[c], 0, 0, 0);
        }
#pragma unroll
        for (int r = 0; r < 4; ++r) {
            const int nd = n0 + lg * 4 + r;
            const float dn = dinv[nd];
            half4 hv;
#pragma unroll
            for (int c = 0; c < 4; ++c) hv[c] = (half_t)(acc[c][r] * dn);
            *(half4*)(g + (size_t)nd * 64 + 4 * cl) = hv;
        }
    }
}

// g2 = (relu(dinv*s + b1) @ W2) * dinv   [fp16 in/out]
__global__ __launch_bounds__(256) void k_mm2(
    const float* __restrict__ W2, const float* __restrict__ b1,
    const float* __restrict__ dinv,
    const half_t* __restrict__ s, half_t* __restrict__ g)
{
    const int lane = threadIdx.x & 63;
    const int lg = lane >> 4, cl = lane & 15;
    const int wid = blockIdx.x * (blockDim.x >> 6) + (threadIdx.x >> 6);
    const int nw  = gridDim.x * (blockDim.x >> 6);

    half8 bf[2][4];
    build_bfrags(W2, lg, cl, bf);
    float bias0[8], bias1[8];
#pragma unroll
    for (int j = 0; j < 8; ++j) {
        bias0[j] = b1[8 * lg + j];
        bias1[j] = b1[32 + 8 * lg + j];
    }
    const f32x4 zacc = {0.f, 0.f, 0.f, 0.f};

    for (int t = wid; t < NNODES / 16; t += nw) {
        const int n0 = t * 16;
        const int na = n0 + cl;
        const float dna = dinv[na];
        half8 s0 = *(const half8*)(s + (size_t)na * 64 + 8 * lg);
        half8 s1 = *(const half8*)(s + (size_t)na * 64 + 32 + 8 * lg);
        half8 a0, a1;
#pragma unroll
        for (int j = 0; j < 8; ++j) {
            a0[j] = (half_t)fmaxf(fmaf(dna, (float)s0[j], bias0[j]), 0.0f);
            a1[j] = (half_t)fmaxf(fmaf(dna, (float)s1[j], bias1[j]), 0.0f);
        }
        f32x4 acc[4];
#pragma unroll
        for (int c = 0; c < 4; ++c) {
            acc[c] = __builtin_amdgcn_mfma_f32_16x16x32_f16(a0, bf[0][c], zacc, 0, 0, 0);
            acc[c] = __builtin_amdgcn_mfma_f32_16x16x32_f16(a1, bf[1][c], acc[c], 0, 0, 0);
        }
#pragma unroll
        for (int r = 0; r < 4; ++r) {
            const int nd = n0 + lg * 4 + r;
            const float dn = dinv[nd];
            half4 hv;
#pragma unroll
            for (int c = 0; c < 4; ++c) hv[c] = (half_t)(acc[c][r] * dn);
            *(half4*)(g + (size_t)nd * 64 + 4 * cl) = hv;
        }
    }
}

// ---------------- pure CSR gather: s[n] = g[n] + sum_{e in} g[src[e]] ----------------

__global__ __launch_bounds__(256) void k_gather(
    const int* __restrict__ off, const int* __restrict__ csr,
    const half_t* __restrict__ gin, half_t* __restrict__ sout)
{
    const int lane = threadIdx.x & 63;
    const int wid = blockIdx.x * (blockDim.x >> 6) + (threadIdx.x >> 6);
    const int nw  = gridDim.x * (blockDim.x >> 6);

    for (int b = wid; b * 8 < NNODES; b += nw) {
        const int n0 = b * 8;
        int o[8], oe[8];
#pragma unroll
        for (int j = 0; j < 8; ++j) { o[j] = off[n0 + j]; oe[j] = off[n0 + j + 1]; }
        float sum[8];
#pragma unroll
        for (int j = 0; j < 8; ++j) sum[j] = (float)gin[(size_t)(n0 + j) * 64 + lane];

        bool any = false;
#pragma unroll
        for (int j = 0; j < 8; ++j) any |= (o[j] < oe[j]);
        while (any) {
            bool va[8]; int sidx[8];
#pragma unroll
            for (int j = 0; j < 8; ++j) {
                va[j] = o[j] < oe[j];
                sidx[j] = csr[va[j] ? o[j] : 0];        // always issue (safe addr) -> 8 in flight
            }
            float r[8];
#pragma unroll
            for (int j = 0; j < 8; ++j)
                r[j] = (float)gin[(size_t)(va[j] ? sidx[j] : 0) * 64 + lane];
            any = false;
#pragma unroll
            for (int j = 0; j < 8; ++j) {
                if (va[j]) { sum[j] += r[j]; ++o[j]; }
                any |= (o[j] < oe[j]);
            }
        }
#pragma unroll
        for (int j = 0; j < 8; ++j)
            sout[(size_t)(n0 + j) * 64 + lane] = (half_t)sum[j];
    }
}

// ---------------- final: pscore[n] = relu(dinv*s2 + b2) . wp_half ----------------

__global__ __launch_bounds__(256) void k_final(
    const float* __restrict__ dinv, const half_t* __restrict__ s2,
    const float* __restrict__ b2, const float* __restrict__ Wp,
    float* __restrict__ pscore)
{
    const int lane = threadIdx.x & 63;
    const int wid = blockIdx.x * (blockDim.x >> 6) + (threadIdx.x >> 6);
    const int nw  = gridDim.x * (blockDim.x >> 6);
    const float bb = b2[lane], wpu = Wp[lane], wpi = Wp[64 + lane];

    for (int n = wid; n < NNODES; n += nw) {
        float x2 = fmaxf(fmaf(dinv[n], (float)s2[(size_t)n * 64 + lane], bb), 0.0f);
        float t = x2 * ((n < NUSERS) ? wpu : wpi);
#pragma unroll
        for (int o = 32; o > 0; o >>= 1) t += __shfl_xor(t, o, 64);
        if (lane == 0) pscore[n] = t;
    }
}

__global__ void k_pairs(const int* __restrict__ user_ids, const int* __restrict__ item_ids,
                        const float* __restrict__ pscore, const float* __restrict__ bp,
                        float* __restrict__ out)
{
    int b = blockIdx.x * blockDim.x + threadIdx.x;
    if (b < NUSERS)
        out[b] = pscore[user_ids[b]] + pscore[NUSERS + item_ids[b]] + bp[0];
}

// ---------------- launch ----------------
// Workspace layout (byte-exact):
//   deg/cursor :          0 ..   2,000,000   (reused as pscore after k_place)
//   dinv       :  2,000,000 ..   4,000,000
//   offsets    :  4,000,000 ..   6,000,004   (NNODES+1 ints)
//   partials   :  6,000,128 ..   6,007,944
//   csr_src    :  6,008,000 ..  10,808,000
//   bufA (g)   : 10,808,064 ..  74,808,064   (NNODES*64 fp16) — g1 then g2
//   bufB (s)   : 74,808,064 .. 138,808,064   — s1 then s2

extern "C" void kernel_launch(void* const* d_in, const int* in_sizes, int n_in,
                              void* d_out, int out_size, void* d_ws, size_t ws_size,
                              hipStream_t stream)
{
    const float* user_table = (const float*)d_in[0];
    const float* item_table = (const float*)d_in[1];
    const float* W1 = (const float*)d_in[2];
    const float* b1 = (const float*)d_in[3];
    const float* W2 = (const float*)d_in[4];
    const float* b2 = (const float*)d_in[5];
    const float* Wp = (const float*)d_in[6];
    const float* bp = (const float*)d_in[7];
    const int* edge = (const int*)d_in[8];
    const int* uid  = (const int*)d_in[9];
    const int* iid  = (const int*)d_in[10];
    float* out = (float*)d_out;

    const int* src = edge;
    const int* dst = edge + NEDGES;

    char* ws = (char*)d_ws;
    int*    deg      = (int*)   (ws + 0);
    float*  dinv     = (float*) (ws + 2000000);
    int*    offsets  = (int*)   (ws + 4000000);
    int*    partials = (int*)   (ws + 6000128);
    int*    csr_src  = (int*)   (ws + 6008000);
    half_t* bufA     = (half_t*)(ws + 10808064);
    half_t* bufB     = (half_t*)(ws + 74808064);
    float*  pscore   = (float*) (ws + 0);        // aliases deg (dead after k_place)

    k_zero_deg     <<<NBLK, 256, 0, stream>>>(deg);
    k_count_deg    <<<(NEDGES + 255) / 256, 256, 0, stream>>>(dst, deg);
    k_dinv         <<<NBLK, 256, 0, stream>>>(deg, dinv);
    k_block_sums   <<<NBLK, 256, 0, stream>>>(deg, partials);
    k_scan_partials<<<1, 256, 0, stream>>>(partials);
    k_scan_blocks  <<<NBLK, 256, 0, stream>>>(partials, deg, offsets);
    k_place        <<<(NEDGES + 255) / 256, 256, 0, stream>>>(src, dst, deg, csr_src);

    k_mm1   <<<1024, 256, 0, stream>>>(user_table, item_table, uid, iid, W1, dinv, bufA);
    k_gather<<<2048, 256, 0, stream>>>(offsets, csr_src, bufA, bufB);
    k_mm2   <<<1024, 256, 0, stream>>>(W2, b1, dinv, bufB, bufA);
    k_gather<<<2048, 256, 0, stream>>>(offsets, csr_src, bufA, bufB);
    k_final <<<2048, 256, 0, stream>>>(dinv, bufB, b2, Wp, pscore);
    k_pairs <<<(NUSERS + 255) / 256, 256, 0, stream>>>(uid, iid, pscore, bp, out);
}